// Round 10
// baseline (27.551 us; speedup 1.0000x reference)
//
#include <hip/hip_runtime.h>

// Problem constants (match reference):
//   B = 8192 batches, N = 64 antennas, K = 16 users, NOISE = 1.0
//   H: [B, N, K, 2] f32  (re/im interleaved, 32 floats per n-row)
//   P: [B, 2*N*K]  f32  (first N*K = Pr[n][j], second N*K = Pi[n][j])
// Output: scalar f32 = -(1/B) * sum_{b,k} log2(1 + sig/interf)
//
// R10: two batches per wave, in-register software pipeline.
// R6-R9 established: ~24-25us main kernel = ~89% of the 10.2 B/cyc/CU
// streaming ceiling; last uncovered overhead is the once-per-wave load
// drain (wave churn, 8192 short waves). Here each wave does 2 batches:
// batch1's 48 loads are issued (and pinned via sched_barrier) BEFORE
// batch0's MFMA+epilogue, so compute covers the second drain. VGPR stays
// <=128 -> 4 waves/SIMD TLP preserved. Everything else = R6.

typedef short bf16x8 __attribute__((ext_vector_type(8)));
typedef float f32x4  __attribute__((ext_vector_type(4)));
typedef int   i32x4  __attribute__((ext_vector_type(4)));

__device__ __forceinline__ int pk2(float lo, float hi) {
    int r;
    asm("v_cvt_pk_bf16_f32 %0, %1, %2" : "=v"(r) : "v"(lo), "v"(hi));
    return r;   // bf16(lo) low 16b, bf16(hi) high 16b (RNE)
}

__device__ __forceinline__ bf16x8 mk8(const float* v) {  // v[8] -> packed bf16 frag
    i32x4 t;
    #pragma unroll
    for (int i = 0; i < 4; ++i) t[i] = pk2(v[2 * i], v[2 * i + 1]);
    return __builtin_bit_cast(bf16x8, t);
}

__device__ __forceinline__ bf16x8 negbf(bf16x8 a) {      // flip all 8 sign bits
    i32x4 t = __builtin_bit_cast(i32x4, a);
    #pragma unroll
    for (int i = 0; i < 4; ++i) t[i] ^= 0x80008000;
    return __builtin_bit_cast(bf16x8, t);
}

#define MFMA __builtin_amdgcn_mfma_f32_16x16x32_bf16

struct Raw {
    float2 h0[8], h1[8];                  // H halves (n 0..31 / 32..63)
    float pr0[8], pr1[8], pi0[8], pi1[8]; // P halves, re/im
};
struct Frags {
    bf16x8 Ahr0, Ahr1, Ahi0, Ahi1, Bpr0, Bpr1, Bpi0, Bpi1;
};

__device__ __forceinline__ void loadBatch(const float* __restrict__ Hb,
                                          const float* __restrict__ Pb,
                                          int j, int n0, Raw& w) {
    const float* hA = Hb + n0 * 32 + 2 * j;   // (re,im) of H[n][k]
    const float* pB = Pb + n0 * 16 + j;       // Pr[n][j]
    #pragma unroll
    for (int r = 0; r < 8; ++r) {
        w.h0[r] = *reinterpret_cast<const float2*>(hA + r * 32);
        w.h1[r] = *reinterpret_cast<const float2*>(hA + 1024 + r * 32);
        w.pr0[r] = pB[r * 16];
        w.pr1[r] = pB[512 + r * 16];
        w.pi0[r] = pB[1024 + r * 16];
        w.pi1[r] = pB[1536 + r * 16];
    }
}

__device__ __forceinline__ Frags packFrags(const Raw& w) {
    float ar0[8], ai0[8], ar1[8], ai1[8];
    #pragma unroll
    for (int r = 0; r < 8; ++r) {
        ar0[r] = w.h0[r].x; ai0[r] = w.h0[r].y;
        ar1[r] = w.h1[r].x; ai1[r] = w.h1[r].y;
    }
    Frags f;
    f.Ahr0 = mk8(ar0); f.Ahr1 = mk8(ar1);
    f.Ahi0 = mk8(ai0); f.Ahi1 = mk8(ai1);
    f.Bpr0 = mk8(w.pr0); f.Bpr1 = mk8(w.pr1);
    f.Bpi0 = mk8(w.pi0); f.Bpi1 = mk8(w.pi1);
    return f;
}

// Complex 16x16x64 matmul + sum-rate epilogue. Returns the batch's rate,
// identical across all 64 lanes. C/D: col=j=lane&15, row=k=4*g+reg.
__device__ __forceinline__ float batchRate(const Frags& f, int j, int g) {
    f32x4 dr = {0.f, 0.f, 0.f, 0.f}, di = {0.f, 0.f, 0.f, 0.f};
    dr = MFMA(f.Ahr0, f.Bpr0, dr, 0, 0, 0);
    dr = MFMA(f.Ahr1, f.Bpr1, dr, 0, 0, 0);
    dr = MFMA(negbf(f.Ahi0), f.Bpi0, dr, 0, 0, 0);
    dr = MFMA(negbf(f.Ahi1), f.Bpi1, dr, 0, 0, 0);
    di = MFMA(f.Ahr0, f.Bpi0, di, 0, 0, 0);
    di = MFMA(f.Ahr1, f.Bpi1, di, 0, 0, 0);
    di = MFMA(f.Ahi0, f.Bpr0, di, 0, 0, 0);
    di = MFMA(f.Ahi1, f.Bpr1, di, 0, 0, 0);

    float tot[4], sig[4];
    #pragma unroll
    for (int r = 0; r < 4; ++r) {
        const float mag = dr[r] * dr[r] + di[r] * di[r];
        const int k = g * 4 + r;
        tot[r] = mag;
        sig[r] = (j == k) ? mag : 0.0f;
    }
    #pragma unroll
    for (int m = 1; m < 16; m <<= 1) {
        #pragma unroll
        for (int r = 0; r < 4; ++r) {
            tot[r] += __shfl_xor(tot[r], m, 64);
            sig[r] += __shfl_xor(sig[r], m, 64);
        }
    }
    float rate = 0.0f;
    #pragma unroll
    for (int r = 0; r < 4; ++r)
        rate += log2f(1.0f + sig[r] / (tot[r] - sig[r] + 1.0f));
    rate += __shfl_xor(rate, 16, 64);
    rate += __shfl_xor(rate, 32, 64);
    return rate;
}

__global__ __launch_bounds__(256, 2) void sumrate_kernel(
        const float* __restrict__ H, const float* __restrict__ P,
        float* __restrict__ ws) {
    __shared__ float sRate[4];

    const int wave = threadIdx.x >> 6;        // 4 waves/block, 2 batches each
    const int lane = threadIdx.x & 63;
    const int b0   = (blockIdx.x * 4 + wave) * 2;
    const int j    = lane & 15;               // A row (k) and B col (j)
    const int g    = lane >> 4;               // n-slice group 0..3
    const int n0   = g * 8;                   // this lane's base n

    // ---- Pipeline: load0, pack0, issue load1, compute0 under load1 ----
    Raw r0;
    loadBatch(H + (size_t)b0 * 2048, P + (size_t)b0 * 2048, j, n0, r0);
    Frags f0 = packFrags(r0);

    Raw r1;
    loadBatch(H + (size_t)(b0 + 1) * 2048, P + (size_t)(b0 + 1) * 2048,
              j, n0, r1);
    __builtin_amdgcn_sched_barrier(0);        // pin load1 issue above compute0

    float rate = batchRate(f0, j, g);         // covers load1 latency

    Frags f1 = packFrags(r1);
    rate += batchRate(f1, j, g);

    // Combine the block's 4 wave-rates (8 batches) -> one store per block.
    if (lane == 0) sRate[wave] = rate;
    __syncthreads();
    if (threadIdx.x == 0)
        ws[blockIdx.x] = sRate[0] + sRate[1] + sRate[2] + sRate[3];
}

// One 128-thread block reduces the 1024 per-block partials (float4 loads).
__global__ __launch_bounds__(128) void reduce_kernel(
        const float* __restrict__ ws, float* __restrict__ out) {
    __shared__ float sPart[2];
    const float4* w4 = reinterpret_cast<const float4*>(ws);
    float s = 0.0f;
    #pragma unroll
    for (int i = 0; i < 2; ++i) {
        const float4 v = w4[threadIdx.x + i * 128];
        s += (v.x + v.y) + (v.z + v.w);
    }
    #pragma unroll
    for (int m = 1; m < 64; m <<= 1)
        s += __shfl_xor(s, m, 64);

    const int w = threadIdx.x >> 6;
    const int l = threadIdx.x & 63;
    if (l == 0) sPart[w] = s;
    __syncthreads();
    if (threadIdx.x == 0)
        out[0] = (sPart[0] + sPart[1]) * (-1.0f / 8192.0f);
}

extern "C" void kernel_launch(void* const* d_in, const int* in_sizes, int n_in,
                              void* d_out, int out_size, void* d_ws, size_t ws_size,
                              hipStream_t stream) {
    const float* H = (const float*)d_in[0];
    const float* P = (const float*)d_in[1];
    float* out = (float*)d_out;
    float* ws  = (float*)d_ws;   // 1024 floats of per-block rate sums

    // 8192 batches, 2 per wave, 4 waves per 256-thread block -> 1024 blocks
    sumrate_kernel<<<1024, 256, 0, stream>>>(H, P, ws);
    reduce_kernel<<<1, 128, 0, stream>>>(ws, out);
}